// Round 1
// baseline (2020.839 us; speedup 1.0000x reference)
//
#include <hip/hip_runtime.h>

#define NXQ 729
#define M2Q 128
#define MQ  857
#define BQ  16
#define QPEN_ 0.1
#define SIGMA_ 0.1

// workspace offsets (in doubles)
constexpr int OFF_P    = 0;
constexpr int OFF_H2   = OFF_P + BQ*NXQ;
constexpr int OFF_Z    = OFF_H2 + M2Q;
constexpr int OFF_S    = OFF_Z + BQ*NXQ;
constexpr int OFF_LAM  = OFF_S + BQ*MQ;
constexpr int OFF_D    = OFF_LAM + BQ*MQ;
constexpr int OFF_RP   = OFF_D + BQ*MQ;
constexpr int OFF_V    = OFF_RP + BQ*MQ;
constexpr int OFF_AINV = OFF_V + BQ*MQ;
constexpr int OFF_Y    = OFF_AINV + BQ*NXQ;
constexpr int OFF_T    = OFF_Y + BQ*NXQ;
constexpr int OFF_GZ2  = OFF_T + BQ*M2Q;
constexpr int OFF_SG   = OFF_GZ2 + BQ*M2Q;

constexpr int SH_SOLVE_DBL = 128*129 + 736 + 128 + 128 + 128 + 32 + 8; // 17672
constexpr int SH_SOLVE = SH_SOLVE_DBL * 8;                             // 141376 B
constexpr int SH_B     = 4 * 2176 * 8;                                 // 69632 B

__device__ __forceinline__ double wred_sum(double v) {
#pragma unroll
  for (int off = 32; off > 0; off >>= 1) v += __shfl_down(v, off, 64);
  return v;
}
__device__ __forceinline__ double wred_min(double v) {
#pragma unroll
  for (int off = 32; off > 0; off >>= 1) v = fmin(v, __shfl_down(v, off, 64));
  return v;
}

// ---------------------------------------------------------------------------
// S build: S_b = G2 * diag(ainv_b) * G2^T  (128x128 per batch, fp64)
// grid (16 tiles, 16 batches), 256 threads = 4 waves, each wave a k-chunk.
// ---------------------------------------------------------------------------
__global__ __launch_bounds__(256)
void sbuild_kernel(const float* __restrict__ G2, double* __restrict__ ws) {
  const int b = blockIdx.y;
  const int tile = blockIdx.x;
  const int R0 = (tile >> 2) * 32, C0 = (tile & 3) * 32;
  const int tid = threadIdx.x, wave = tid >> 6, lane = tid & 63;
  extern __shared__ double sm[];
  double* As = sm + wave * 2176;   // [kk][r] stride 34, scaled by ainv
  double* Bs = As + 1088;          // [kk][c] stride 34, raw
  const double* __restrict__ ainv = ws + OFF_AINV + b * NXQ;
  const int k0w = wave * 183;
  const int kend = min(k0w + 183, NXQ);
  const int rg4 = (lane >> 3) * 4, cg4 = (lane & 7) * 4;
  double acc[4][4];
#pragma unroll
  for (int i = 0; i < 4; ++i)
#pragma unroll
    for (int j = 0; j < 4; ++j) acc[i][j] = 0.0;

  const int kk = lane & 31;
  for (int ch = 0; ch < 6; ++ch) {
    const int k = k0w + ch * 32 + kk;
    const bool ok = (k < kend);
    const double aik = ok ? ainv[k] : 0.0;
    __syncthreads();
#pragma unroll
    for (int it = 0; it < 16; ++it) {
      const int rr = (it << 1) | (lane >> 5);
      double av = 0.0, bv = 0.0;
      if (ok) {
        av = (double)G2[(R0 + rr) * NXQ + k] * aik;
        bv = (double)G2[(C0 + rr) * NXQ + k];
      }
      As[kk * 34 + rr] = av;
      Bs[kk * 34 + rr] = bv;
    }
    __syncthreads();
#pragma unroll 8
    for (int q = 0; q < 32; ++q) {
      const double a0 = As[q*34 + rg4 + 0], a1 = As[q*34 + rg4 + 1],
                   a2 = As[q*34 + rg4 + 2], a3 = As[q*34 + rg4 + 3];
      const double b0 = Bs[q*34 + cg4 + 0], b1 = Bs[q*34 + cg4 + 1],
                   b2 = Bs[q*34 + cg4 + 2], b3 = Bs[q*34 + cg4 + 3];
      acc[0][0] += a0*b0; acc[0][1] += a0*b1; acc[0][2] += a0*b2; acc[0][3] += a0*b3;
      acc[1][0] += a1*b0; acc[1][1] += a1*b1; acc[1][2] += a1*b2; acc[1][3] += a1*b3;
      acc[2][0] += a2*b0; acc[2][1] += a2*b1; acc[2][2] += a2*b2; acc[2][3] += a2*b3;
      acc[3][0] += a3*b0; acc[3][1] += a3*b1; acc[3][2] += a3*b2; acc[3][3] += a3*b3;
    }
  }
  __syncthreads();
  // dump per-wave partials flat into own region
#pragma unroll
  for (int i = 0; i < 4; ++i)
#pragma unroll
    for (int j = 0; j < 4; ++j)
      As[(rg4 + i) * 32 + cg4 + j] = acc[i][j];
  __syncthreads();
  double* __restrict__ Sgb = ws + OFF_SG + b * (M2Q * M2Q);
  for (int idx = tid; idx < 1024; idx += 256) {
    const double v = sm[idx] + sm[2176 + idx] + sm[4352 + idx] + sm[6528 + idx];
    Sgb[(R0 + (idx >> 5)) * M2Q + C0 + (idx & 31)] = v;
  }
}

// ---------------------------------------------------------------------------
// solve kernel: one block per batch. mode==0: init+prep. mode==1: solve+update(+prep)
// ---------------------------------------------------------------------------
__global__ __launch_bounds__(1024)
void solve_kernel(const float* __restrict__ puzzles, const float* __restrict__ G2,
                  const float* __restrict__ z2in, const float* __restrict__ s2in,
                  double* __restrict__ ws, float* __restrict__ out,
                  const int mode, const int last) {
  const int b = blockIdx.x;
  const int tid = threadIdx.x, wave = tid >> 6, lane = tid & 63;
  extern __shared__ double sm[];
  double (*Sl)[129] = (double(*)[129])sm;     // 128x129
  double* dzs  = sm + 128 * 129;              // 736
  double* us   = dzs + 736;                   // 128 (t -> u)
  double* g2b  = us + 128;                    // 128 (Gdz2 / q2)
  double* invd = g2b + 128;                   // 128
  double* red  = invd + 128;                  // 32
  double* sc   = red + 32;                    // 8

  double* p    = ws + OFF_P    + b * NXQ;
  double* h2g  = ws + OFF_H2;
  double* z    = ws + OFF_Z    + b * NXQ;
  double* s    = ws + OFF_S    + b * MQ;
  double* lam  = ws + OFF_LAM  + b * MQ;
  double* dd   = ws + OFF_D    + b * MQ;
  double* rp   = ws + OFF_RP   + b * MQ;
  double* vv   = ws + OFF_V    + b * MQ;
  double* ainv = ws + OFF_AINV + b * NXQ;
  double* yv   = ws + OFF_Y    + b * NXQ;
  double* tv   = ws + OFF_T    + b * M2Q;
  double* gz2  = ws + OFF_GZ2  + b * M2Q;
  double* Sgb  = ws + OFF_SG   + b * M2Q * M2Q;

  if (mode == 0) {
    for (int i = tid; i < NXQ; i += 1024) { z[i] = 0.0; p[i] = -(double)puzzles[b * NXQ + i]; }
    for (int i = tid; i < MQ;  i += 1024) { s[i] = 1.0; lam[i] = 1.0; }
    for (int i = tid; i < M2Q; i += 1024) gz2[i] = 0.0;
    // h2 = G2 @ z2 + s2 (computed redundantly by each block; identical values)
    for (int r = wave; r < M2Q; r += 16) {
      double acc = 0.0;
      for (int k = lane; k < NXQ; k += 64) acc += (double)G2[r * NXQ + k] * (double)z2in[k];
      acc = wred_sum(acc);
      if (lane == 0) h2g[r] = acc + (double)s2in[r];
    }
    __syncthreads();
  } else {
    // ---- Phase A: load S into LDS, add D2^{-1} diag, load t
    for (int idx = tid; idx < M2Q * M2Q; idx += 1024)
      Sl[idx >> 7][idx & 127] = Sgb[idx];
    if (tid < M2Q) us[tid] = tv[tid];
    __syncthreads();
    if (tid < M2Q) Sl[tid][tid] += s[NXQ + tid] / lam[NXQ + tid];
    __syncthreads();

    // ---- Phase B: blocked Cholesky (NB=16) with integrated forward substitution
    for (int kb = 0; kb < 8; ++kb) {
      const int K0 = kb * 16, J0 = K0 + 16, T = 128 - J0;
      if (wave == 0) {
        const int r = lane & 15;
        double a[16];
#pragma unroll
        for (int c = 0; c < 16; ++c) a[c] = Sl[K0 + r][K0 + c];
        double x = us[K0 + r];
#pragma unroll
        for (int c = 0; c < 16; ++c) {
          const double dcc = __shfl(a[c], c, 64);
          const double rs  = 1.0 / sqrt(dcc);
          a[c] *= rs;                         // column c scaled -> L[r][c] for r>=c
          const double uc = __shfl(x, c, 64) * rs;   // forward subst value
          if (r > c) x -= a[c] * uc;
#pragma unroll
          for (int k2 = c + 1; k2 < 16; ++k2) {
            const double lkc = __shfl(a[c], k2, 64);
            a[k2] -= a[c] * lkc;
          }
          if (lane == c) { invd[K0 + c] = rs; us[K0 + c] = uc; }
        }
        if (lane < 16) {
#pragma unroll
          for (int c = 0; c < 16; ++c) if (c <= r) Sl[K0 + r][K0 + c] = a[c];
        }
      }
      __syncthreads();
      if (kb < 7) {
        // panel: L21 = A21 * L11^{-T}, one thread per row
        const int rr = J0 + tid;
        if (rr < 128) {
          double l[16];
#pragma unroll
          for (int c = 0; c < 16; ++c) l[c] = Sl[rr][K0 + c];
#pragma unroll
          for (int c = 0; c < 16; ++c) {
            double acc = l[c];
#pragma unroll
            for (int j = 0; j < 16; ++j) if (j < c) acc -= l[j] * Sl[K0 + c][K0 + j];
            l[c] = acc * invd[K0 + c];
          }
#pragma unroll
          for (int c = 0; c < 16; ++c) Sl[rr][K0 + c] = l[c];
        }
        __syncthreads();
        // forward-subst trailing update of u
        if (tid < T) {
          const int i = J0 + tid;
          double acc = us[i];
#pragma unroll
          for (int c = 0; c < 16; ++c) acc -= Sl[i][K0 + c] * us[K0 + c];
          us[i] = acc;
        }
        // SYRK: A22 -= L21 * L21^T (lower)
        for (int ii = tid; ii < T * T; ii += 1024) {
          const int i = J0 + ii / T, j = J0 + ii % T;
          if (j <= i) {
            double acc = Sl[i][j];
#pragma unroll
            for (int c = 0; c < 16; ++c) acc -= Sl[i][K0 + c] * Sl[j][K0 + c];
            Sl[i][j] = acc;
          }
        }
      }
      __syncthreads();
    }

    // ---- Phase C: backward substitution L^T u = u'
    for (int kb = 7; kb >= 0; --kb) {
      const int K0 = kb * 16;
      if (kb < 7) {
        const int c = K0 + wave;   // 16 waves, one column each
        double acc = 0.0;
        for (int k = K0 + 16 + lane; k < 128; k += 64) acc += Sl[k][c] * us[k];
        acc = wred_sum(acc);
        if (lane == 0) us[c] -= acc;
      }
      __syncthreads();
      if (wave == 0) {
        const int r = lane & 15;
        double lt[16];
#pragma unroll
        for (int c = 0; c < 16; ++c) lt[c] = Sl[K0 + c][K0 + r];  // L^T[r][c]
        double x = us[K0 + r];
#pragma unroll
        for (int cc = 0; cc < 16; ++cc) {
          const int c = 15 - cc;
          const double uc = __shfl(x, c, 64) * invd[K0 + c];
          if (r < c) x -= lt[c] * uc;
          if (lane == c) us[K0 + c] = uc;
        }
      }
      __syncthreads();
    }

    // ---- Phase D: w = G2^T u ; dz = y - ainv*w ; Gdz2 = D2inv*u (exact identity)
    if (tid < M2Q) g2b[tid] = (s[NXQ + tid] / lam[NXQ + tid]) * us[tid];
    for (int k = tid; k < NXQ; k += 1024) {
      double acc0 = 0.0, acc1 = 0.0;
      for (int r = 0; r < M2Q; r += 2) {
        acc0 += (double)G2[r * NXQ + k] * us[r];
        acc1 += (double)G2[(r + 1) * NXQ + k] * us[r + 1];
      }
      dzs[k] = yv[k] - ainv[k] * (acc0 + acc1);
    }
    __syncthreads();

    // ---- Phase E: alpha (fraction-to-boundary)
    double lmin = 1e300;
    for (int i = tid; i < MQ; i += 1024) {
      double dsi, dlami;
      if (i < NXQ) {
        const double dzi = dzs[i];
        dsi = dzi - rp[i];
        dlami = vv[i] - dd[i] * dzi;
      } else {
        const double g = g2b[i - NXQ];
        dsi = -rp[i] - g;
        dlami = vv[i] + dd[i] * g;
      }
      if (dsi < 0.0)   lmin = fmin(lmin, -s[i] / dsi);
      if (dlami < 0.0) lmin = fmin(lmin, -lam[i] / dlami);
    }
    lmin = wred_min(lmin);
    if (lane == 0) red[wave] = lmin;
    __syncthreads();
    if (tid == 0) {
      double m = red[0];
      for (int w = 1; w < 16; ++w) m = fmin(m, red[w]);
      sc[0] = fmin(1.0, 0.99 * m);
    }
    __syncthreads();

    // ---- Phase F: update state, write output
    const double alpha = sc[0];
    for (int i = tid; i < NXQ; i += 1024) {
      const double zi = z[i] + alpha * dzs[i];
      z[i] = zi;
      out[b * NXQ + i] = (float)zi;
    }
    for (int i = tid; i < MQ; i += 1024) {
      double dsi, dlami;
      if (i < NXQ) {
        const double dzi = dzs[i];
        dsi = dzi - rp[i];
        dlami = vv[i] - dd[i] * dzi;
      } else {
        const double g = g2b[i - NXQ];
        dsi = -rp[i] - g;
        dlami = vv[i] + dd[i] * g;
      }
      s[i]   += alpha * dsi;
      lam[i] += alpha * dlami;
    }
    if (tid < M2Q) gz2[tid] += alpha * g2b[tid];
    __syncthreads();
    if (last) return;
  }

  // ---- PREP for next iteration: d, rp, mu, v, rhs, ainv, y, t
  double musum = 0.0;
  for (int i = tid; i < MQ; i += 1024) {
    const double si = s[i], li = lam[i];
    const double di = li / si;
    dd[i] = di;
    const double rpi = (i < NXQ) ? (si - z[i]) : (gz2[i - NXQ] + si - h2g[i - NXQ]);
    rp[i] = rpi;
    musum += si * li;
  }
  musum = wred_sum(musum);
  if (lane == 0) red[wave] = musum;
  __syncthreads();
  if (tid == 0) {
    double t = 0.0;
    for (int w = 0; w < 16; ++w) t += red[w];
    sc[1] = SIGMA_ * (t / (double)MQ);
  }
  __syncthreads();
  const double smu = sc[1];
  for (int i = tid; i < MQ; i += 1024) {
    const double si = s[i], li = lam[i];
    const double vi = smu / si - li + dd[i] * rp[i];
    vv[i] = vi;
    if (i >= NXQ) g2b[i - NXQ] = li + vi;   // q2 = lam2 + v2
  }
  __syncthreads();
  // rhs = -(QPEN z + p - lam1 - v1 + G2^T q2); ainv; y
  for (int k = tid; k < NXQ; k += 1024) {
    double acc0 = 0.0, acc1 = 0.0;
    for (int r = 0; r < M2Q; r += 2) {
      acc0 += (double)G2[r * NXQ + k] * g2b[r];
      acc1 += (double)G2[(r + 1) * NXQ + k] * g2b[r + 1];
    }
    const double rhsk = -(QPEN_ * z[k] + p[k] - lam[k] - vv[k] + (acc0 + acc1));
    const double ai = 1.0 / (QPEN_ + dd[k]);
    ainv[k] = ai;
    yv[k] = ai * rhsk;
  }
  __syncthreads();
  // t = G2 @ y
  for (int r = wave; r < M2Q; r += 16) {
    double acc = 0.0;
    for (int k = lane; k < NXQ; k += 64) acc += (double)G2[r * NXQ + k] * yv[k];
    acc = wred_sum(acc);
    if (lane == 0) tv[r] = acc;
  }
}

extern "C" void kernel_launch(void* const* d_in, const int* in_sizes, int n_in,
                              void* d_out, int out_size, void* d_ws, size_t ws_size,
                              hipStream_t stream) {
  const float* puzzles = (const float*)d_in[0];
  const float* G2      = (const float*)d_in[1];
  const float* z2      = (const float*)d_in[2];
  const float* s2      = (const float*)d_in[3];
  float* out = (float*)d_out;
  double* ws = (double*)d_ws;

  // opt-in to >64KB dynamic LDS (gfx950 has 160 KiB/CU); sticky per-process.
  (void)hipFuncSetAttribute(reinterpret_cast<const void*>(&solve_kernel),
                            hipFuncAttributeMaxDynamicSharedMemorySize, SH_SOLVE);
  (void)hipFuncSetAttribute(reinterpret_cast<const void*>(&sbuild_kernel),
                            hipFuncAttributeMaxDynamicSharedMemorySize, SH_B);

  // init + prep for iteration 1
  solve_kernel<<<dim3(BQ), dim3(1024), SH_SOLVE, stream>>>(puzzles, G2, z2, s2, ws, out, 0, 0);
  for (int it = 0; it < 10; ++it) {
    sbuild_kernel<<<dim3(16, BQ), dim3(256), SH_B, stream>>>(G2, ws);
    solve_kernel<<<dim3(BQ), dim3(1024), SH_SOLVE, stream>>>(puzzles, G2, z2, s2, ws, out, 1,
                                                             (it == 9) ? 1 : 0);
  }
}

// Round 4
// 1471.232 us; speedup vs baseline: 1.3736x; 1.3736x over previous
//
#include <hip/hip_runtime.h>
#include <math.h>

#define NXQ 729
#define M2Q 128
#define MQ  857
#define BQ  16
#define QPEN_ 0.1
#define SIGMA_ 0.1

typedef double d4 __attribute__((ext_vector_type(4)));

// workspace offsets (in doubles)
constexpr int OFF_P    = 0;
constexpr int OFF_H2   = OFF_P + BQ*NXQ;
constexpr int OFF_Z    = OFF_H2 + M2Q;
constexpr int OFF_S    = OFF_Z + BQ*NXQ;
constexpr int OFF_LAM  = OFF_S + BQ*MQ;
constexpr int OFF_D    = OFF_LAM + BQ*MQ;
constexpr int OFF_RP   = OFF_D + BQ*MQ;
constexpr int OFF_V    = OFF_RP + BQ*MQ;
constexpr int OFF_AINV = OFF_V + BQ*MQ;
constexpr int OFF_Y    = OFF_AINV + BQ*NXQ;
constexpr int OFF_T    = OFF_Y + BQ*NXQ;
constexpr int OFF_GZ2  = OFF_T + BQ*M2Q;
constexpr int OFF_SG   = OFF_GZ2 + BQ*M2Q;

// solve LDS layout (doubles)
constexpr int L_SL   = 0;                 // 128 x 129
constexpr int L_DZS  = 128*129;           // 736
constexpr int L_US   = L_DZS + 736;       // 128
constexpr int L_G2B  = L_US + 128;        // 128
constexpr int L_INVD = L_G2B + 128;       // 128
constexpr int L_RED  = L_INVD + 128;      // 8
constexpr int L_RED2 = L_RED + 8;         // 512 (16 x 32)
constexpr int L_SC   = L_RED2 + 512;      // 8
constexpr int SH_SOLVE_DBL = L_SC + 8;
constexpr int SH_SOLVE = SH_SOLVE_DBL * 8;  // ~145 KB
constexpr int SH_B     = 4 * 2176 * 8;      // 69632 B

__device__ __forceinline__ double wred_sum(double v) {
#pragma unroll
  for (int off = 32; off > 0; off >>= 1) v += __shfl_down(v, off, 64);
  return v;
}
__device__ __forceinline__ double wred_min(double v) {
#pragma unroll
  for (int off = 32; off > 0; off >>= 1) v = fmin(v, __shfl_down(v, off, 64));
  return v;
}
__device__ __forceinline__ double rsqrt64(double x) { return rsqrt(x); }

// ---------------------------------------------------------------------------
// S build: S_b = G2 * diag(ainv_b) * G2^T  (128x128 per batch, fp64)
// ---------------------------------------------------------------------------
__global__ __launch_bounds__(256)
void sbuild_kernel(const float* __restrict__ G2, double* __restrict__ ws) {
  const int b = blockIdx.y;
  const int tile = blockIdx.x;
  const int R0 = (tile >> 2) * 32, C0 = (tile & 3) * 32;
  const int tid = threadIdx.x, wave = tid >> 6, lane = tid & 63;
  extern __shared__ double sm[];
  double* As = sm + wave * 2176;
  double* Bs = As + 1088;
  const double* __restrict__ ainv = ws + OFF_AINV + b * NXQ;
  const int k0w = wave * 183;
  const int kend = min(k0w + 183, NXQ);
  const int rg4 = (lane >> 3) * 4, cg4 = (lane & 7) * 4;
  double acc[4][4];
#pragma unroll
  for (int i = 0; i < 4; ++i)
#pragma unroll
    for (int j = 0; j < 4; ++j) acc[i][j] = 0.0;

  const int kk = lane & 31;
  for (int ch = 0; ch < 6; ++ch) {
    const int k = k0w + ch * 32 + kk;
    const bool ok = (k < kend);
    const double aik = ok ? ainv[k] : 0.0;
    __syncthreads();
#pragma unroll
    for (int it = 0; it < 16; ++it) {
      const int rr = (it << 1) | (lane >> 5);
      double av = 0.0, bv = 0.0;
      if (ok) {
        av = (double)G2[(R0 + rr) * NXQ + k] * aik;
        bv = (double)G2[(C0 + rr) * NXQ + k];
      }
      As[kk * 34 + rr] = av;
      Bs[kk * 34 + rr] = bv;
    }
    __syncthreads();
#pragma unroll 8
    for (int q = 0; q < 32; ++q) {
      const double a0 = As[q*34 + rg4 + 0], a1 = As[q*34 + rg4 + 1],
                   a2 = As[q*34 + rg4 + 2], a3 = As[q*34 + rg4 + 3];
      const double b0 = Bs[q*34 + cg4 + 0], b1 = Bs[q*34 + cg4 + 1],
                   b2 = Bs[q*34 + cg4 + 2], b3 = Bs[q*34 + cg4 + 3];
      acc[0][0] += a0*b0; acc[0][1] += a0*b1; acc[0][2] += a0*b2; acc[0][3] += a0*b3;
      acc[1][0] += a1*b0; acc[1][1] += a1*b1; acc[1][2] += a1*b2; acc[1][3] += a1*b3;
      acc[2][0] += a2*b0; acc[2][1] += a2*b1; acc[2][2] += a2*b2; acc[2][3] += a2*b3;
      acc[3][0] += a3*b0; acc[3][1] += a3*b1; acc[3][2] += a3*b2; acc[3][3] += a3*b3;
    }
  }
  __syncthreads();
#pragma unroll
  for (int i = 0; i < 4; ++i)
#pragma unroll
    for (int j = 0; j < 4; ++j)
      As[(rg4 + i) * 32 + cg4 + j] = acc[i][j];
  __syncthreads();
  double* __restrict__ Sgb = ws + OFF_SG + b * (M2Q * M2Q);
  for (int idx = tid; idx < 1024; idx += 256) {
    const double v = sm[idx] + sm[2176 + idx] + sm[4352 + idx] + sm[6528 + idx];
    Sgb[(R0 + (idx >> 5)) * M2Q + C0 + (idx & 31)] = v;
  }
}

// ---------------------------------------------------------------------------
// solve kernel: one block per batch, 512 threads (8 waves).
// ---------------------------------------------------------------------------
__global__ __launch_bounds__(512, 2)
void solve_kernel(const float* __restrict__ puzzles, const float* __restrict__ G2,
                  const float* __restrict__ z2in, const float* __restrict__ s2in,
                  double* __restrict__ ws, float* __restrict__ out,
                  const int mode, const int last) {
  const int b = blockIdx.x;
  const int tid = threadIdx.x, wave = tid >> 6, lane = tid & 63;
  extern __shared__ double sm[];
  double (*Sl)[129] = (double(*)[129])(sm + L_SL);
  double* dzs  = sm + L_DZS;
  double* us   = sm + L_US;
  double* g2b  = sm + L_G2B;
  double* invd = sm + L_INVD;
  double* red  = sm + L_RED;
  double* red2 = sm + L_RED2;
  double* sc   = sm + L_SC;

  double* p    = ws + OFF_P    + b * NXQ;
  double* h2g  = ws + OFF_H2;
  double* z    = ws + OFF_Z    + b * NXQ;
  double* s    = ws + OFF_S    + b * MQ;
  double* lam  = ws + OFF_LAM  + b * MQ;
  double* dd   = ws + OFF_D    + b * MQ;
  double* rp   = ws + OFF_RP   + b * MQ;
  double* vv   = ws + OFF_V    + b * MQ;
  double* ainv = ws + OFF_AINV + b * NXQ;
  double* yv   = ws + OFF_Y    + b * NXQ;
  double* tv   = ws + OFF_T    + b * M2Q;
  double* gz2  = ws + OFF_GZ2  + b * M2Q;
  double* Sgb  = ws + OFF_SG   + b * M2Q * M2Q;

  if (mode == 0) {
    for (int i = tid; i < NXQ; i += 512) { z[i] = 0.0; p[i] = -(double)puzzles[b * NXQ + i]; }
    for (int i = tid; i < MQ;  i += 512) { s[i] = 1.0; lam[i] = 1.0; }
    for (int i = tid; i < M2Q; i += 512) gz2[i] = 0.0;
    for (int r = wave; r < M2Q; r += 8) {
      double acc = 0.0;
      for (int k = lane; k < NXQ; k += 64) acc += (double)G2[r * NXQ + k] * (double)z2in[k];
      acc = wred_sum(acc);
      if (lane == 0) h2g[r] = acc + (double)s2in[r];
    }
    __syncthreads();
  } else {
    // ---- Phase A: S -> LDS, add D2^{-1} diag, u = t
    {
      const double2* __restrict__ Sg2 = (const double2*)Sgb;
      for (int idx = tid; idx < M2Q * M2Q / 2; idx += 512) {
        const double2 v = Sg2[idx];
        const int r = idx >> 6, c = (idx & 63) * 2;
        Sl[r][c] = v.x; Sl[r][c + 1] = v.y;
      }
    }
    if (tid < M2Q) us[tid] = tv[tid];
    __syncthreads();
    if (tid < M2Q) Sl[tid][tid] += s[NXQ + tid] / lam[NXQ + tid];
    __syncthreads();

    // ---- Runtime probe of the f64 MFMA C/D register->(row,col) mapping.
    // D=A*B with A[:,0]=i, B[0,:]=1 makes every acc register hold its own ROW
    // index; the mirror probe yields the COLUMN index. SYRK below then works
    // under ANY C/D layout (transposed, strided, etc.).
    int rowm[4], colm[4];
    {
      const int rc = lane & 15, kq = lane >> 4;
      const double avr = (kq == 0) ? (double)rc : 0.0;  // A[i][0] = i
      const double bv1 = (kq == 0) ? 1.0 : 0.0;         // B[0][j] = 1
      const double av1 = (kq == 0) ? 1.0 : 0.0;         // A[i][0] = 1
      const double bvc = (kq == 0) ? (double)rc : 0.0;  // B[0][j] = j
      d4 zero = {0.0, 0.0, 0.0, 0.0};
      d4 dr = __builtin_amdgcn_mfma_f64_16x16x4f64(avr, bv1, zero, 0, 0, 0);
      d4 dc = __builtin_amdgcn_mfma_f64_16x16x4f64(av1, bvc, zero, 0, 0, 0);
#pragma unroll
      for (int e = 0; e < 4; ++e) { rowm[e] = (int)dr[e]; colm[e] = (int)dc[e]; }
    }

    // ---- Phase B: blocked Cholesky (NB=16), fwd-subst integrated as extra TRSM row
    for (int kb = 0; kb < 8; ++kb) {
      const int K0 = kb * 16, J0 = K0 + 16, T = 128 - J0;

      // micro-Cholesky of 16x16 diag block: wave 0, lanes 0..15 (lane = row)
      if (wave == 0 && lane < 16) {
        const int r = lane;
        double a[16];
#pragma unroll
        for (int c = 0; c < 16; ++c) a[c] = Sl[K0 + r][K0 + c];
#pragma unroll
        for (int c = 0; c < 16; ++c) {
          const double dcc = __shfl(a[c], c, 64);
          const double rs = rsqrt64(dcc);
          a[c] *= rs;
          if (lane == c) invd[K0 + c] = rs;
#pragma unroll
          for (int k2 = c + 1; k2 < 16; ++k2) {
            const double lkc = __shfl(a[c], k2, 64);
            a[k2] = fma(-a[c], lkc, a[k2]);
          }
        }
#pragma unroll
        for (int c = 0; c < 16; ++c) Sl[K0 + r][K0 + c] = a[c];
      }
      __syncthreads();

      // TRSM: rows J0..127 (threads 0..T-1) + u-row (thread T). Right-looking.
      if (tid <= T) {
        const bool isU = (tid == T);
        double l[16];
        if (isU) {
#pragma unroll
          for (int c = 0; c < 16; ++c) l[c] = us[K0 + c];
        } else {
#pragma unroll
          for (int c = 0; c < 16; ++c) l[c] = Sl[J0 + tid][K0 + c];
        }
#pragma unroll
        for (int c = 0; c < 16; ++c) {
          const double lc = l[c] * invd[K0 + c];
          l[c] = lc;
#pragma unroll
          for (int k2 = c + 1; k2 < 16; ++k2)
            l[k2] = fma(-lc, Sl[K0 + k2][K0 + c], l[k2]);
        }
        if (isU) {
#pragma unroll
          for (int c = 0; c < 16; ++c) us[K0 + c] = l[c];
        } else {
#pragma unroll
          for (int c = 0; c < 16; ++c) Sl[J0 + tid][K0 + c] = l[c];
        }
      }
      __syncthreads();

      if (kb < 7) {
        // u trailing update: u2 -= L21 * u1
        if (tid < T) {
          double acc = 0.0;
#pragma unroll
          for (int c = 0; c < 16; ++c) acc = fma(Sl[J0 + tid][K0 + c], us[K0 + c], acc);
          us[J0 + tid] -= acc;
        }
        // SYRK via f64 MFMA: A22 -= L21 * L21^T, full-square tile coverage.
        // C/D addressed through the runtime-probed rowm/colm maps.
        const int Tb = 7 - kb;
        const int rc = lane & 15, kq = lane >> 4;
        for (int idx = wave; idx < Tb * Tb; idx += 8) {
          const int i0 = J0 + (idx / Tb) * 16;
          const int j0 = J0 + (idx % Tb) * 16;
          d4 acc;
#pragma unroll
          for (int e = 0; e < 4; ++e) acc[e] = Sl[i0 + rowm[e]][j0 + colm[e]];
#pragma unroll
          for (int m = 0; m < 4; ++m) {
            const double av = -Sl[i0 + rc][K0 + 4 * m + kq];
            const double bv =  Sl[j0 + rc][K0 + 4 * m + kq];
            acc = __builtin_amdgcn_mfma_f64_16x16x4f64(av, bv, acc, 0, 0, 0);
          }
#pragma unroll
          for (int e = 0; e < 4; ++e) Sl[i0 + rowm[e]][j0 + colm[e]] = acc[e];
        }
      }
      __syncthreads();
    }

    // ---- Phase C: backward substitution L^T u = u'
    for (int kb = 7; kb >= 0; --kb) {
      const int K0 = kb * 16;
      if (kb < 7) {
        const int c = tid & 15, ch = tid >> 4;  // ch in 0..31
        double part = 0.0;
        for (int k = K0 + 16 + ch; k < 128; k += 32) part = fma(Sl[k][K0 + c], us[k], part);
        red2[c * 32 + ch] = part;
        __syncthreads();
        if (tid < 16) {
          double acc = 0.0;
#pragma unroll
          for (int q = 0; q < 32; ++q) acc += red2[tid * 32 + q];
          us[K0 + tid] -= acc;
        }
        __syncthreads();
      }
      if (wave == 0 && lane < 16) {
        const int j = lane;
        double colv[16];
#pragma unroll
        for (int c = 0; c < 16; ++c) colv[c] = Sl[K0 + c][K0 + j];
        double x = us[K0 + j];
        const double iv = invd[K0 + j];
#pragma unroll
        for (int cc = 0; cc < 16; ++cc) {
          const int c = 15 - cc;
          const double xiv = x * iv;
          const double uc = __shfl(xiv, c, 64);
          if (j == c) x = xiv;
          else if (j < c) x = fma(-colv[c], uc, x);
        }
        us[K0 + j] = x;
      }
      __syncthreads();
    }

    // ---- Phase D: Gdz2 = D2inv*u (exact identity); dz = y - ainv*(G2^T u)
    if (tid < M2Q) g2b[tid] = (s[NXQ + tid] / lam[NXQ + tid]) * us[tid];
    __syncthreads();
    for (int k = tid; k < NXQ; k += 512) {
      double a0 = 0.0, a1 = 0.0;
      for (int r = 0; r < M2Q; r += 2) {
        a0 = fma((double)G2[r * NXQ + k], us[r], a0);
        a1 = fma((double)G2[(r + 1) * NXQ + k], us[r + 1], a1);
      }
      dzs[k] = yv[k] - ainv[k] * (a0 + a1);
    }
    __syncthreads();

    // ---- Phase E: alpha (fraction-to-boundary)
    double lmin = 1e300;
    for (int i = tid; i < MQ; i += 512) {
      double dsi, dlami;
      if (i < NXQ) {
        const double dzi = dzs[i];
        dsi = dzi - rp[i];
        dlami = vv[i] - dd[i] * dzi;
      } else {
        const double g = g2b[i - NXQ];
        dsi = -rp[i] - g;
        dlami = vv[i] + dd[i] * g;
      }
      if (dsi < 0.0)   lmin = fmin(lmin, -s[i] / dsi);
      if (dlami < 0.0) lmin = fmin(lmin, -lam[i] / dlami);
    }
    lmin = wred_min(lmin);
    if (lane == 0) red[wave] = lmin;
    __syncthreads();
    if (tid == 0) {
      double m = red[0];
      for (int w = 1; w < 8; ++w) m = fmin(m, red[w]);
      sc[0] = fmin(1.0, 0.99 * m);
    }
    __syncthreads();

    // ---- Phase F: update state, write output
    const double alpha = sc[0];
    for (int i = tid; i < NXQ; i += 512) {
      const double zi = z[i] + alpha * dzs[i];
      z[i] = zi;
      out[b * NXQ + i] = (float)zi;
    }
    for (int i = tid; i < MQ; i += 512) {
      double dsi, dlami;
      if (i < NXQ) {
        const double dzi = dzs[i];
        dsi = dzi - rp[i];
        dlami = vv[i] - dd[i] * dzi;
      } else {
        const double g = g2b[i - NXQ];
        dsi = -rp[i] - g;
        dlami = vv[i] + dd[i] * g;
      }
      s[i]   += alpha * dsi;
      lam[i] += alpha * dlami;
    }
    if (tid < M2Q) gz2[tid] += alpha * g2b[tid];
    __syncthreads();
    if (last) return;
  }

  // ---- PREP for next iteration: d, rp, mu, v, rhs, ainv, y, t
  double musum = 0.0;
  for (int i = tid; i < MQ; i += 512) {
    const double si = s[i], li = lam[i];
    dd[i] = li / si;
    const double rpi = (i < NXQ) ? (si - z[i]) : (gz2[i - NXQ] + si - h2g[i - NXQ]);
    rp[i] = rpi;
    musum += si * li;
  }
  musum = wred_sum(musum);
  if (lane == 0) red[wave] = musum;
  __syncthreads();
  if (tid == 0) {
    double t = 0.0;
    for (int w = 0; w < 8; ++w) t += red[w];
    sc[1] = SIGMA_ * (t / (double)MQ);
  }
  __syncthreads();
  const double smu = sc[1];
  for (int i = tid; i < MQ; i += 512) {
    const double si = s[i], li = lam[i];
    const double vi = smu / si - li + dd[i] * rp[i];
    vv[i] = vi;
    if (i >= NXQ) g2b[i - NXQ] = li + vi;   // q2 = lam2 + v2
  }
  __syncthreads();
  for (int k = tid; k < NXQ; k += 512) {
    double a0 = 0.0, a1 = 0.0;
    for (int r = 0; r < M2Q; r += 2) {
      a0 = fma((double)G2[r * NXQ + k], g2b[r], a0);
      a1 = fma((double)G2[(r + 1) * NXQ + k], g2b[r + 1], a1);
    }
    const double rhsk = -(QPEN_ * z[k] + p[k] - lam[k] - vv[k] + a0 + a1);
    const double ai = 1.0 / (QPEN_ + dd[k]);
    ainv[k] = ai;
    yv[k] = ai * rhsk;
  }
  __syncthreads();
  for (int r = wave; r < M2Q; r += 8) {
    double acc = 0.0;
    for (int k = lane; k < NXQ; k += 64) acc = fma((double)G2[r * NXQ + k], yv[k], acc);
    acc = wred_sum(acc);
    if (lane == 0) tv[r] = acc;
  }
}

extern "C" void kernel_launch(void* const* d_in, const int* in_sizes, int n_in,
                              void* d_out, int out_size, void* d_ws, size_t ws_size,
                              hipStream_t stream) {
  const float* puzzles = (const float*)d_in[0];
  const float* G2      = (const float*)d_in[1];
  const float* z2      = (const float*)d_in[2];
  const float* s2      = (const float*)d_in[3];
  float* out = (float*)d_out;
  double* ws = (double*)d_ws;

  (void)hipFuncSetAttribute(reinterpret_cast<const void*>(&solve_kernel),
                            hipFuncAttributeMaxDynamicSharedMemorySize, SH_SOLVE);
  (void)hipFuncSetAttribute(reinterpret_cast<const void*>(&sbuild_kernel),
                            hipFuncAttributeMaxDynamicSharedMemorySize, SH_B);

  solve_kernel<<<dim3(BQ), dim3(512), SH_SOLVE, stream>>>(puzzles, G2, z2, s2, ws, out, 0, 0);
  for (int it = 0; it < 10; ++it) {
    sbuild_kernel<<<dim3(16, BQ), dim3(256), SH_B, stream>>>(G2, ws);
    solve_kernel<<<dim3(BQ), dim3(512), SH_SOLVE, stream>>>(puzzles, G2, z2, s2, ws, out, 1,
                                                            (it == 9) ? 1 : 0);
  }
}

// Round 5
// 1250.671 us; speedup vs baseline: 1.6158x; 1.1764x over previous
//
#include <hip/hip_runtime.h>
#include <math.h>

#define NXQ 729
#define M2Q 128
#define MQ  857
#define BQ  16
#define QPEN_ 0.1
#define SIGMA_ 0.1

typedef double d4 __attribute__((ext_vector_type(4)));

// workspace offsets (in doubles)
constexpr int OFF_P    = 0;                      // 16x729
constexpr int OFF_H2   = OFF_P + BQ*NXQ;         // 128
constexpr int OFF_Z    = OFF_H2 + M2Q;           // 16x729
constexpr int OFF_S    = OFF_Z + BQ*NXQ;         // 16x857
constexpr int OFF_LAM  = OFF_S + BQ*MQ;          // 16x857
constexpr int OFF_D    = OFF_LAM + BQ*MQ;        // 16x857
constexpr int OFF_RP   = OFF_D + BQ*MQ;          // 16x857
constexpr int OFF_V    = OFF_RP + BQ*MQ;         // 16x857
constexpr int OFF_AINV = OFF_V + BQ*MQ;          // 16x729
constexpr int OFF_Y    = OFF_AINV + BQ*NXQ;      // 16x729
constexpr int OFF_T    = OFF_Y + BQ*NXQ;         // 16x128
constexpr int OFF_GZ2  = OFF_T + BQ*M2Q;         // 16x128
constexpr int OFF_Q2   = OFF_GZ2 + BQ*M2Q;       // 16x128
constexpr int OFF_USOL = OFF_Q2 + BQ*M2Q;        // 16x128
constexpr int OFF_G2B  = OFF_USOL + BQ*M2Q;      // 16x128
constexpr int OFF_RHS  = OFF_G2B + BQ*M2Q;       // 16x729 (+64 slack)
constexpr int OFF_AMIN = OFF_RHS + BQ*NXQ + 64;  // 16 (as ull)
constexpr int OFF_SG   = OFF_AMIN + 64;          // 16x128x128
constexpr int OFF_DZS  = OFF_SG;                 // 16x768 ALIASES SG prefix
                                                 // (S consumed by solveK before dzK writes;
                                                 //  sbuild rewrites SG after updK reads DZS)

// solve LDS layout (doubles)
constexpr int L_SL   = 0;                 // 128 x 129
constexpr int L_US   = 128*129;           // 128
constexpr int L_INVD = L_US + 128;        // 128
constexpr int L_RED2 = L_INVD + 128;      // 512
constexpr int L_RED  = L_RED2 + 512;      // 8
constexpr int SH_SOLVE = (L_RED + 8) * 8; // ~138 KB
constexpr int SH_B     = (4*2176 + 128) * 8;  // 70656 B

__device__ __forceinline__ double wred_sum(double v) {
#pragma unroll
  for (int off = 32; off > 0; off >>= 1) v += __shfl_down(v, off, 64);
  return v;
}
__device__ __forceinline__ double wred_min(double v) {
#pragma unroll
  for (int off = 32; off > 0; off >>= 1) v = fmin(v, __shfl_down(v, off, 64));
  return v;
}
__device__ __forceinline__ double rsqrt64(double x) { return rsqrt(x); }

// ---------------------------------------------------------------------------
// init: state init + h2 + elementwise first-iteration prep (mu=1 exactly)
// ---------------------------------------------------------------------------
__global__ __launch_bounds__(512)
void init_kernel(const float* __restrict__ puzzles, const float* __restrict__ G2,
                 const float* __restrict__ z2in, const float* __restrict__ s2in,
                 double* __restrict__ ws) {
  const int b = blockIdx.x;
  const int tid = threadIdx.x, wave = tid >> 6, lane = tid & 63;
  __shared__ double h2l[128];
  double* p    = ws + OFF_P    + b * NXQ;
  double* z    = ws + OFF_Z    + b * NXQ;
  double* s    = ws + OFF_S    + b * MQ;
  double* lam  = ws + OFF_LAM  + b * MQ;
  double* dd   = ws + OFF_D    + b * MQ;
  double* rp   = ws + OFF_RP   + b * MQ;
  double* vv   = ws + OFF_V    + b * MQ;
  double* ainv = ws + OFF_AINV + b * NXQ;
  double* gz2  = ws + OFF_GZ2  + b * M2Q;
  double* q2v  = ws + OFF_Q2   + b * M2Q;

  for (int i = tid; i < NXQ; i += 512) {
    p[i] = -(double)puzzles[b * NXQ + i];
    z[i] = 0.0;
    ainv[i] = 1.0 / (QPEN_ + 1.0);
  }
  for (int i = tid; i < MQ; i += 512) { s[i] = 1.0; lam[i] = 1.0; dd[i] = 1.0; }
  if (tid < M2Q) gz2[tid] = 0.0;
  // h2 = G2 @ z2 + s2 (each block computes all rows; identical values to ws)
  for (int r = wave; r < M2Q; r += 8) {
    double acc = 0.0;
    for (int k = lane; k < NXQ; k += 64) acc += (double)G2[r * NXQ + k] * (double)z2in[k];
    acc = wred_sum(acc);
    if (lane == 0) { h2l[r] = acc + (double)s2in[r]; ws[OFF_H2 + r] = h2l[r]; }
  }
  __syncthreads();
  // prep with mu = mean(s*lam) = 1 exactly
  const double smu = SIGMA_ * 1.0;
  for (int i = tid; i < MQ; i += 512) {
    const double rpi = (i < NXQ) ? 1.0 : (1.0 - h2l[i - NXQ]);  // s - z / gz2+s-h2
    rp[i] = rpi;
    const double vi = smu / 1.0 - 1.0 + 1.0 * rpi;
    vv[i] = vi;
    if (i >= NXQ) q2v[i - NXQ] = 1.0 + vi;
  }
}

// ---------------------------------------------------------------------------
// prep matvec: rhs = -(0.1 z + p - lam1 - v1 + G2^T q2); y = ainv*rhs
// grid (12 kchunks x 16 batches), 512 thr: thread = (k within 64, row-quad)
// ---------------------------------------------------------------------------
__global__ __launch_bounds__(512)
void prep_kernel(const float* __restrict__ G2, double* __restrict__ ws) {
  const int b = blockIdx.y, c0 = blockIdx.x * 64;
  const int tid = threadIdx.x, kk = tid & 63, rq = tid >> 6;
  const int k = c0 + kk;
  __shared__ double uvec[128];
  __shared__ double part[8 * 64];
  if (tid < 128) uvec[tid] = ws[OFF_Q2 + b * M2Q + tid];
  __syncthreads();
  const int kg = (k < NXQ) ? k : (NXQ - 1);
  double acc = 0.0;
  const float* gp = G2 + (rq * 16) * NXQ + kg;
#pragma unroll
  for (int j = 0; j < 16; ++j) acc = fma((double)gp[j * NXQ], uvec[rq * 16 + j], acc);
  part[rq * 64 + kk] = acc;
  __syncthreads();
  if (tid < 64 && k < NXQ) {
    double w = 0.0;
#pragma unroll
    for (int q = 0; q < 8; ++q) w += part[q * 64 + tid];
    const double rhsk = -(QPEN_ * ws[OFF_Z + b * NXQ + k] + ws[OFF_P + b * NXQ + k]
                          - ws[OFF_LAM + b * MQ + k] - ws[OFF_V + b * MQ + k] + w);
    ws[OFF_RHS + b * NXQ + k] = rhsk;
    ws[OFF_Y + b * NXQ + k] = ws[OFF_AINV + b * NXQ + k] * rhsk;
  }
}

// ---------------------------------------------------------------------------
// S build: S_b = G2 * diag(ainv_b) * G2^T ; C0==0 blocks also t = G2*y
// (t[r] = sum_k G2[r][k]*ainv[k]*rhs[k] = As-row . rhs)
// ---------------------------------------------------------------------------
__global__ __launch_bounds__(256)
void sbuild_kernel(const float* __restrict__ G2, double* __restrict__ ws) {
  const int b = blockIdx.y;
  const int tile = blockIdx.x;
  const int R0 = (tile >> 2) * 32, C0 = (tile & 3) * 32;
  const int tid = threadIdx.x, wave = tid >> 6, lane = tid & 63;
  extern __shared__ double sm[];
  double* As = sm + wave * 2176;
  double* Bs = As + 1088;
  double* twl = sm + 4 * 2176;   // 128: per-wave t partials
  const double* __restrict__ ainv = ws + OFF_AINV + b * NXQ;
  const double* __restrict__ rhsv = ws + OFF_RHS + b * NXQ;
  const int k0w = wave * 183;
  const int kend = min(k0w + 183, NXQ);
  const int rg4 = (lane >> 3) * 4, cg4 = (lane & 7) * 4;
  double acc[4][4];
#pragma unroll
  for (int i = 0; i < 4; ++i)
#pragma unroll
    for (int j = 0; j < 4; ++j) acc[i][j] = 0.0;
  double treg = 0.0;
  const bool doT = (C0 == 0) && (lane < 32);
  const int rr2 = lane & 31;

  const int kk = lane & 31;
  for (int ch = 0; ch < 6; ++ch) {
    const int k = k0w + ch * 32 + kk;
    const bool ok = (k < kend);
    const double aik = ok ? ainv[k] : 0.0;
    __syncthreads();
#pragma unroll
    for (int it = 0; it < 16; ++it) {
      const int rr = (it << 1) | (lane >> 5);
      double av = 0.0, bv = 0.0;
      if (ok) {
        av = (double)G2[(R0 + rr) * NXQ + k] * aik;
        bv = (double)G2[(C0 + rr) * NXQ + k];
      }
      As[kk * 34 + rr] = av;
      Bs[kk * 34 + rr] = bv;
    }
    __syncthreads();
#pragma unroll 8
    for (int q = 0; q < 32; ++q) {
      const double a0 = As[q*34 + rg4 + 0], a1 = As[q*34 + rg4 + 1],
                   a2 = As[q*34 + rg4 + 2], a3 = As[q*34 + rg4 + 3];
      const double b0 = Bs[q*34 + cg4 + 0], b1 = Bs[q*34 + cg4 + 1],
                   b2 = Bs[q*34 + cg4 + 2], b3 = Bs[q*34 + cg4 + 3];
      acc[0][0] += a0*b0; acc[0][1] += a0*b1; acc[0][2] += a0*b2; acc[0][3] += a0*b3;
      acc[1][0] += a1*b0; acc[1][1] += a1*b1; acc[1][2] += a1*b2; acc[1][3] += a1*b3;
      acc[2][0] += a2*b0; acc[2][1] += a2*b1; acc[2][2] += a2*b2; acc[2][3] += a2*b3;
      acc[3][0] += a3*b0; acc[3][1] += a3*b1; acc[3][2] += a3*b2; acc[3][3] += a3*b3;
    }
    if (doT) {
      const int kb0 = k0w + ch * 32;
#pragma unroll
      for (int q = 0; q < 32; ++q) {
        const int kq2 = kb0 + q;
        const double rv = (kq2 < kend) ? rhsv[kq2] : 0.0;
        treg = fma(As[q * 34 + rr2], rv, treg);
      }
    }
  }
  __syncthreads();
  if (doT) twl[wave * 32 + rr2] = treg;
#pragma unroll
  for (int i = 0; i < 4; ++i)
#pragma unroll
    for (int j = 0; j < 4; ++j)
      As[(rg4 + i) * 32 + cg4 + j] = acc[i][j];
  __syncthreads();
  double* __restrict__ Sgb = ws + OFF_SG + b * (M2Q * M2Q);
  for (int idx = tid; idx < 1024; idx += 256) {
    const double v = sm[idx] + sm[2176 + idx] + sm[4352 + idx] + sm[6528 + idx];
    Sgb[(R0 + (idx >> 5)) * M2Q + C0 + (idx & 31)] = v;
  }
  if (C0 == 0 && tid < 32)
    ws[OFF_T + b * M2Q + R0 + tid] = twl[tid] + twl[32 + tid] + twl[64 + tid] + twl[96 + tid];
}

// ---------------------------------------------------------------------------
// solve: factor K = S + D2inv and solve K u = t. 16 blocks x 512 thr.
// Writes u, g2b = D2inv*u, and seeds amin with the m2-part ratio min.
// ---------------------------------------------------------------------------
__global__ __launch_bounds__(512, 2)
void solve_kernel(double* __restrict__ ws) {
  const int b = blockIdx.x;
  const int tid = threadIdx.x, wave = tid >> 6, lane = tid & 63;
  extern __shared__ double sm[];
  double (*Sl)[129] = (double(*)[129])(sm + L_SL);
  double* us   = sm + L_US;
  double* invd = sm + L_INVD;
  double* red2 = sm + L_RED2;
  double* red  = sm + L_RED;

  double* s    = ws + OFF_S    + b * MQ;
  double* lam  = ws + OFF_LAM  + b * MQ;
  double* Sgb  = ws + OFF_SG   + b * M2Q * M2Q;

  // ---- Phase A: S -> LDS, add D2^{-1} diag, u = t
  {
    const double2* __restrict__ Sg2 = (const double2*)Sgb;
    for (int idx = tid; idx < M2Q * M2Q / 2; idx += 512) {
      const double2 v = Sg2[idx];
      const int r = idx >> 6, c = (idx & 63) * 2;
      Sl[r][c] = v.x; Sl[r][c + 1] = v.y;
    }
  }
  if (tid < M2Q) us[tid] = ws[OFF_T + b * M2Q + tid];
  __syncthreads();
  if (tid < M2Q) Sl[tid][tid] += s[NXQ + tid] / lam[NXQ + tid];
  __syncthreads();

  // ---- probe f64 MFMA C/D mapping (verified technique from round 4)
  int rowm[4], colm[4];
  {
    const int rc = lane & 15, kq = lane >> 4;
    const double avr = (kq == 0) ? (double)rc : 0.0;
    const double bv1 = (kq == 0) ? 1.0 : 0.0;
    const double av1 = (kq == 0) ? 1.0 : 0.0;
    const double bvc = (kq == 0) ? (double)rc : 0.0;
    d4 zero = {0.0, 0.0, 0.0, 0.0};
    d4 dr = __builtin_amdgcn_mfma_f64_16x16x4f64(avr, bv1, zero, 0, 0, 0);
    d4 dc = __builtin_amdgcn_mfma_f64_16x16x4f64(av1, bvc, zero, 0, 0, 0);
#pragma unroll
    for (int e = 0; e < 4; ++e) { rowm[e] = (int)dr[e]; colm[e] = (int)dc[e]; }
  }

  // ---- Phase B: blocked Cholesky (NB=16) + integrated forward substitution
  for (int kb = 0; kb < 8; ++kb) {
    const int K0 = kb * 16, J0 = K0 + 16, T = 128 - J0;
    if (wave == 0 && lane < 16) {
      const int r = lane;
      double a[16];
#pragma unroll
      for (int c = 0; c < 16; ++c) a[c] = Sl[K0 + r][K0 + c];
#pragma unroll
      for (int c = 0; c < 16; ++c) {
        const double dcc = __shfl(a[c], c, 64);
        const double rs = rsqrt64(dcc);
        a[c] *= rs;
        if (lane == c) invd[K0 + c] = rs;
#pragma unroll
        for (int k2 = c + 1; k2 < 16; ++k2) {
          const double lkc = __shfl(a[c], k2, 64);
          a[k2] = fma(-a[c], lkc, a[k2]);
        }
      }
#pragma unroll
      for (int c = 0; c < 16; ++c) Sl[K0 + r][K0 + c] = a[c];
    }
    __syncthreads();

    if (tid <= T) {
      const bool isU = (tid == T);
      double l[16];
      if (isU) {
#pragma unroll
        for (int c = 0; c < 16; ++c) l[c] = us[K0 + c];
      } else {
#pragma unroll
        for (int c = 0; c < 16; ++c) l[c] = Sl[J0 + tid][K0 + c];
      }
#pragma unroll
      for (int c = 0; c < 16; ++c) {
        const double lc = l[c] * invd[K0 + c];
        l[c] = lc;
#pragma unroll
        for (int k2 = c + 1; k2 < 16; ++k2)
          l[k2] = fma(-lc, Sl[K0 + k2][K0 + c], l[k2]);
      }
      if (isU) {
#pragma unroll
        for (int c = 0; c < 16; ++c) us[K0 + c] = l[c];
      } else {
#pragma unroll
        for (int c = 0; c < 16; ++c) Sl[J0 + tid][K0 + c] = l[c];
      }
    }
    __syncthreads();

    if (kb < 7) {
      if (tid < T) {
        double acc = 0.0;
#pragma unroll
        for (int c = 0; c < 16; ++c) acc = fma(Sl[J0 + tid][K0 + c], us[K0 + c], acc);
        us[J0 + tid] -= acc;
      }
      const int Tb = 7 - kb;
      const int rc = lane & 15, kq = lane >> 4;
      for (int idx = wave; idx < Tb * Tb; idx += 8) {
        const int i0 = J0 + (idx / Tb) * 16;
        const int j0 = J0 + (idx % Tb) * 16;
        d4 acc;
#pragma unroll
        for (int e = 0; e < 4; ++e) acc[e] = Sl[i0 + rowm[e]][j0 + colm[e]];
#pragma unroll
        for (int m = 0; m < 4; ++m) {
          const double av = -Sl[i0 + rc][K0 + 4 * m + kq];
          const double bv =  Sl[j0 + rc][K0 + 4 * m + kq];
          acc = __builtin_amdgcn_mfma_f64_16x16x4f64(av, bv, acc, 0, 0, 0);
        }
#pragma unroll
        for (int e = 0; e < 4; ++e) Sl[i0 + rowm[e]][j0 + colm[e]] = acc[e];
      }
    }
    __syncthreads();
  }

  // ---- Phase C: backward substitution L^T u = u'
  for (int kb = 7; kb >= 0; --kb) {
    const int K0 = kb * 16;
    if (kb < 7) {
      const int c = tid & 15, ch = tid >> 4;
      double part = 0.0;
      for (int k = K0 + 16 + ch; k < 128; k += 32) part = fma(Sl[k][K0 + c], us[k], part);
      red2[c * 32 + ch] = part;
      __syncthreads();
      if (tid < 16) {
        double acc = 0.0;
#pragma unroll
        for (int q = 0; q < 32; ++q) acc += red2[tid * 32 + q];
        us[K0 + tid] -= acc;
      }
      __syncthreads();
    }
    if (wave == 0 && lane < 16) {
      const int j = lane;
      double colv[16];
#pragma unroll
      for (int c = 0; c < 16; ++c) colv[c] = Sl[K0 + c][K0 + j];
      double x = us[K0 + j];
      const double iv = invd[K0 + j];
#pragma unroll
      for (int cc = 0; cc < 16; ++cc) {
        const int c = 15 - cc;
        const double xiv = x * iv;
        const double uc = __shfl(xiv, c, 64);
        if (j == c) x = xiv;
        else if (j < c) x = fma(-colv[c], uc, x);
      }
      us[K0 + j] = x;
    }
    __syncthreads();
  }

  // ---- tail: write u, g2b = D2inv*u; seed amin with m2-part ratio min
  double lmin = 1e300;
  if (tid < M2Q) {
    const double u = us[tid];
    ws[OFF_USOL + b * M2Q + tid] = u;
    const double g = (s[NXQ + tid] / lam[NXQ + tid]) * u;
    ws[OFF_G2B + b * M2Q + tid] = g;
    const int i = NXQ + tid;
    const double dsi = -ws[OFF_RP + b * MQ + i] - g;
    const double dlami = ws[OFF_V + b * MQ + i] + ws[OFF_D + b * MQ + i] * g;
    if (dsi < 0.0)   lmin = fmin(lmin, -s[i] / dsi);
    if (dlami < 0.0) lmin = fmin(lmin, -lam[i] / dlami);
  }
  if (tid < 128) {
    lmin = wred_min(lmin);
    if (lane == 0) red[wave] = lmin;
  }
  __syncthreads();
  if (tid == 0) {
    const double m = fmin(red[0], red[1]);
    ((unsigned long long*)ws)[OFF_AMIN + b] = (unsigned long long)__double_as_longlong(m);
  }
}

// ---------------------------------------------------------------------------
// dz matvec: dz = y - ainv*(G2^T u); per-chunk ratio min -> atomicMin
// grid (12 x 16), 512 thr
// ---------------------------------------------------------------------------
__global__ __launch_bounds__(512)
void dz_kernel(const float* __restrict__ G2, double* __restrict__ ws) {
  const int b = blockIdx.y, c0 = blockIdx.x * 64;
  const int tid = threadIdx.x, kk = tid & 63, rq = tid >> 6;
  const int k = c0 + kk;
  __shared__ double uvec[128];
  __shared__ double part[8 * 64];
  __shared__ double redm[1];
  if (tid < 128) uvec[tid] = ws[OFF_USOL + b * M2Q + tid];
  __syncthreads();
  const int kg = (k < NXQ) ? k : (NXQ - 1);
  double acc = 0.0;
  const float* gp = G2 + (rq * 16) * NXQ + kg;
#pragma unroll
  for (int j = 0; j < 16; ++j) acc = fma((double)gp[j * NXQ], uvec[rq * 16 + j], acc);
  part[rq * 64 + kk] = acc;
  __syncthreads();
  double lmin = 1e300;
  if (tid < 64) {
    if (k < NXQ) {
      double w = 0.0;
#pragma unroll
      for (int q = 0; q < 8; ++q) w += part[q * 64 + tid];
      const double dz = ws[OFF_Y + b * NXQ + k] - ws[OFF_AINV + b * NXQ + k] * w;
      ws[OFF_DZS + b * 768 + k] = dz;
      const double dsi = dz - ws[OFF_RP + b * MQ + k];
      const double dlami = ws[OFF_V + b * MQ + k] - ws[OFF_D + b * MQ + k] * dz;
      if (dsi < 0.0)   lmin = fmin(lmin, -ws[OFF_S + b * MQ + k] / dsi);
      if (dlami < 0.0) lmin = fmin(lmin, -ws[OFF_LAM + b * MQ + k] / dlami);
    }
    lmin = wred_min(lmin);
    if (tid == 0) redm[0] = lmin;
  }
  __syncthreads();
  if (tid == 0)
    atomicMin((unsigned long long*)ws + OFF_AMIN + b,
              (unsigned long long)__double_as_longlong(redm[0]));
}

// ---------------------------------------------------------------------------
// update + elementwise prep. 16 blocks x 512 thr.
// ---------------------------------------------------------------------------
__global__ __launch_bounds__(512)
void upd_kernel(double* __restrict__ ws, float* __restrict__ out, const int last) {
  const int b = blockIdx.x;
  const int tid = threadIdx.x, wave = tid >> 6, lane = tid & 63;
  __shared__ double red[8];
  __shared__ double sc2[2];
  double* z    = ws + OFF_Z    + b * NXQ;
  double* s    = ws + OFF_S    + b * MQ;
  double* lam  = ws + OFF_LAM  + b * MQ;
  double* dd   = ws + OFF_D    + b * MQ;
  double* rp   = ws + OFF_RP   + b * MQ;
  double* vv   = ws + OFF_V    + b * MQ;
  double* gz2  = ws + OFF_GZ2  + b * M2Q;

  if (tid == 0) {
    const double m = __longlong_as_double((long long)((unsigned long long*)ws)[OFF_AMIN + b]);
    sc2[0] = fmin(1.0, 0.99 * m);
  }
  __syncthreads();
  const double alpha = sc2[0];
  for (int i = tid; i < NXQ; i += 512) {
    const double dz = ws[OFF_DZS + b * 768 + i];
    const double dsi = dz - rp[i];
    const double dlami = vv[i] - dd[i] * dz;
    s[i] += alpha * dsi;
    lam[i] += alpha * dlami;
    const double zi = z[i] + alpha * dz;
    z[i] = zi;
    out[b * NXQ + i] = (float)zi;
  }
  if (tid < M2Q) {
    const int i = NXQ + tid;
    const double g = ws[OFF_G2B + b * M2Q + tid];
    const double dsi = -rp[i] - g;
    const double dlami = vv[i] + dd[i] * g;
    s[i] += alpha * dsi;
    lam[i] += alpha * dlami;
    gz2[tid] += alpha * g;
  }
  __syncthreads();
  if (last) return;

  double musum = 0.0;
  for (int i = tid; i < MQ; i += 512) {
    const double si = s[i], li = lam[i];
    dd[i] = li / si;
    const double rpi = (i < NXQ) ? (si - z[i]) : (gz2[i - NXQ] + si - ws[OFF_H2 + i - NXQ]);
    rp[i] = rpi;
    musum += si * li;
  }
  musum = wred_sum(musum);
  if (lane == 0) red[wave] = musum;
  __syncthreads();
  if (tid == 0) {
    double t = 0.0;
    for (int w = 0; w < 8; ++w) t += red[w];
    sc2[1] = SIGMA_ * (t / (double)MQ);
  }
  __syncthreads();
  const double smu = sc2[1];
  for (int i = tid; i < MQ; i += 512) {
    const double si = s[i], li = lam[i];
    const double vi = smu / si - li + dd[i] * rp[i];
    vv[i] = vi;
    if (i >= NXQ) ws[OFF_Q2 + b * M2Q + i - NXQ] = li + vi;
    else ws[OFF_AINV + b * NXQ + i] = 1.0 / (QPEN_ + dd[i]);
  }
}

extern "C" void kernel_launch(void* const* d_in, const int* in_sizes, int n_in,
                              void* d_out, int out_size, void* d_ws, size_t ws_size,
                              hipStream_t stream) {
  const float* puzzles = (const float*)d_in[0];
  const float* G2      = (const float*)d_in[1];
  const float* z2      = (const float*)d_in[2];
  const float* s2      = (const float*)d_in[3];
  float* out = (float*)d_out;
  double* ws = (double*)d_ws;

  (void)hipFuncSetAttribute(reinterpret_cast<const void*>(&solve_kernel),
                            hipFuncAttributeMaxDynamicSharedMemorySize, SH_SOLVE);
  (void)hipFuncSetAttribute(reinterpret_cast<const void*>(&sbuild_kernel),
                            hipFuncAttributeMaxDynamicSharedMemorySize, SH_B);

  init_kernel<<<dim3(BQ), dim3(512), 0, stream>>>(puzzles, G2, z2, s2, ws);
  prep_kernel<<<dim3(12, BQ), dim3(512), 0, stream>>>(G2, ws);
  sbuild_kernel<<<dim3(16, BQ), dim3(256), SH_B, stream>>>(G2, ws);
  for (int it = 0; it < 10; ++it) {
    solve_kernel<<<dim3(BQ), dim3(512), SH_SOLVE, stream>>>(ws);
    dz_kernel<<<dim3(12, BQ), dim3(512), 0, stream>>>(G2, ws);
    upd_kernel<<<dim3(BQ), dim3(512), 0, stream>>>(ws, out, (it == 9) ? 1 : 0);
    if (it < 9) {
      prep_kernel<<<dim3(12, BQ), dim3(512), 0, stream>>>(G2, ws);
      sbuild_kernel<<<dim3(16, BQ), dim3(256), SH_B, stream>>>(G2, ws);
    }
  }
}